// Round 1
// baseline (6688.152 us; speedup 1.0000x reference)
//
#include <hip/hip_runtime.h>
#include <math.h>

#define N_NODES  100000
#define N_EDGES  1600000
#define N_GRAPHS 1000
#define F_IN     9
#define HID      64

// ---------------------------------------------------------------------------
// Workspace layout (floats):
//   [0)              cnt   : N_NODES            (in-degree)
//   [N)              s1    : N_NODES*9          (scatter sum of x)
//   [10N)            s2    : N_NODES*64         (scatter sum of h1)
//   [74N)            pool  : N_GRAPHS*64        (graph-sum of h2)
//   [74N+64G)        gcnt  : N_GRAPHS           (nodes per graph)
//   [74N+65G)        h1    : N_NODES*64         (layer-1 output, not zeroed)
// Zeroed region = first 74*N_NODES + 65*N_GRAPHS floats (one memset).
// ---------------------------------------------------------------------------

__global__ void scatter1_kernel(const int* __restrict__ ei,
                                const float* __restrict__ x,
                                float* __restrict__ s1,
                                float* __restrict__ cnt) {
    int e = blockIdx.x * blockDim.x + threadIdx.x;
    if (e >= N_EDGES) return;
    int src = ei[e];
    int dst = ei[N_EDGES + e];
    atomicAdd(&cnt[dst], 1.0f);
    #pragma unroll
    for (int k = 0; k < F_IN; ++k)
        atomicAdd(&s1[dst * F_IN + k], x[src * F_IN + k]);
}

__global__ void node_l1_kernel(const float* __restrict__ x,
                               const float* __restrict__ s1,
                               const float* __restrict__ cnt,
                               const float* __restrict__ Wl1,
                               const float* __restrict__ Wr1,
                               const float* __restrict__ b1,
                               float* __restrict__ h1) {
    int t = blockIdx.x * blockDim.x + threadIdx.x;
    if (t >= N_NODES * HID) return;
    int n = t >> 6;
    int j = t & 63;
    float inv = 1.0f / fmaxf(cnt[n], 1.0f);
    float acc = b1[j];
    #pragma unroll
    for (int k = 0; k < F_IN; ++k) {
        acc += s1[n * F_IN + k] * inv * Wl1[k * HID + j];
        acc += x[n * F_IN + k] * Wr1[k * HID + j];
    }
    h1[t] = fmaxf(acc, 0.0f);
}

// one thread per (edge, 16-float chunk): 4 chunks per edge
__global__ void scatter2_kernel(const int* __restrict__ ei,
                                const float* __restrict__ h1,
                                float* __restrict__ s2) {
    long long t = (long long)blockIdx.x * blockDim.x + threadIdx.x;
    if (t >= (long long)N_EDGES * 4) return;
    int e = (int)(t >> 2);
    int c = ((int)t & 3) * 16;
    int src = ei[e];
    int dst = ei[N_EDGES + e];
    const float4* hp = (const float4*)&h1[src * HID + c];
    float* sp = &s2[dst * HID + c];
    #pragma unroll
    for (int q = 0; q < 4; ++q) {
        float4 v = hp[q];
        atomicAdd(&sp[q * 4 + 0], v.x);
        atomicAdd(&sp[q * 4 + 1], v.y);
        atomicAdd(&sp[q * 4 + 2], v.z);
        atomicAdd(&sp[q * 4 + 3], v.w);
    }
}

// 256 threads = 4 nodes x 64 features; N_NODES*64 is divisible by 256
__global__ void node_l2_pool_kernel(const float* __restrict__ h1,
                                    const float* __restrict__ s2,
                                    const float* __restrict__ cnt,
                                    const float* __restrict__ Wl2,
                                    const float* __restrict__ Wr2,
                                    const float* __restrict__ b2,
                                    const int* __restrict__ batch,
                                    float* __restrict__ pool,
                                    float* __restrict__ gcnt) {
    __shared__ float sa[4][HID];
    __shared__ float sh[4][HID];
    int t = blockIdx.x * blockDim.x + threadIdx.x;
    int n = t >> 6;
    int j = t & 63;
    int ln = threadIdx.x >> 6;          // local node 0..3
    float inv = 1.0f / fmaxf(cnt[n], 1.0f);
    sa[ln][j] = s2[n * HID + j] * inv;
    sh[ln][j] = h1[n * HID + j];
    __syncthreads();
    float acc = b2[j];
    #pragma unroll 8
    for (int k = 0; k < HID; ++k) {
        acc += sa[ln][k] * Wl2[k * HID + j];
        acc += sh[ln][k] * Wr2[k * HID + j];
    }
    int g = batch[n];
    atomicAdd(&pool[g * HID + j], acc);
    if (j == 0) atomicAdd(&gcnt[g], 1.0f);
}

// 32 lanes per graph: lane j computes hm[j], then shuffle-reduce hm.Wm2
__global__ void mlp_kernel(const float* __restrict__ pool,
                           const float* __restrict__ gcnt,
                           const float* __restrict__ Wm1,
                           const float* __restrict__ bm1,
                           const float* __restrict__ Wm2,
                           const float* __restrict__ bm2,
                           float* __restrict__ out) {
    int t = blockIdx.x * blockDim.x + threadIdx.x;
    int g = t >> 5;
    int j = t & 31;
    if (g >= N_GRAPHS) return;
    float inv = 1.0f / fmaxf(gcnt[g], 1.0f);
    float acc = bm1[j];
    #pragma unroll 8
    for (int k = 0; k < HID; ++k)
        acc += pool[g * HID + k] * inv * Wm1[k * 32 + j];
    float hm = fmaxf(acc, 0.0f) * Wm2[j];
    #pragma unroll
    for (int off = 16; off > 0; off >>= 1)
        hm += __shfl_down(hm, off, 32);
    if (j == 0) {
        float o = hm + bm2[0];
        out[g] = 1.0f / (1.0f + expf(-o));
    }
}

extern "C" void kernel_launch(void* const* d_in, const int* in_sizes, int n_in,
                              void* d_out, int out_size, void* d_ws, size_t ws_size,
                              hipStream_t stream) {
    const float* x    = (const float*)d_in[0];
    const int*   ei   = (const int*)d_in[1];
    // d_in[2] = edge_attr (unused, all zeros)
    const int*   batch= (const int*)d_in[3];
    const float* Wl1  = (const float*)d_in[4];
    const float* Wr1  = (const float*)d_in[5];
    const float* b1   = (const float*)d_in[6];
    const float* Wl2  = (const float*)d_in[7];
    const float* Wr2  = (const float*)d_in[8];
    const float* b2   = (const float*)d_in[9];
    const float* Wm1  = (const float*)d_in[10];
    const float* bm1  = (const float*)d_in[11];
    const float* Wm2  = (const float*)d_in[12];
    const float* bm2  = (const float*)d_in[13];
    float* out = (float*)d_out;

    float* ws   = (float*)d_ws;
    float* cnt  = ws;
    float* s1   = ws + N_NODES;
    float* s2   = ws + (size_t)10 * N_NODES;
    float* pool = ws + (size_t)74 * N_NODES;
    float* gcnt = ws + (size_t)74 * N_NODES + (size_t)64 * N_GRAPHS;
    float* h1   = ws + (size_t)74 * N_NODES + (size_t)65 * N_GRAPHS;

    size_t zero_floats = (size_t)74 * N_NODES + (size_t)65 * N_GRAPHS;
    hipMemsetAsync(d_ws, 0, zero_floats * sizeof(float), stream);

    {   // scatter1: one thread per edge
        int threads = 256, blocks = (N_EDGES + threads - 1) / threads;
        scatter1_kernel<<<blocks, threads, 0, stream>>>(ei, x, s1, cnt);
    }
    {   // node layer 1: one thread per (node, feature)
        int threads = 256, blocks = (N_NODES * HID) / threads;
        node_l1_kernel<<<blocks, threads, 0, stream>>>(x, s1, cnt, Wl1, Wr1, b1, h1);
    }
    {   // scatter2: 4 chunk-threads per edge
        int threads = 256;
        long long total = (long long)N_EDGES * 4;
        int blocks = (int)((total + threads - 1) / threads);
        scatter2_kernel<<<blocks, threads, 0, stream>>>(ei, h1, s2);
    }
    {   // node layer 2 + pool
        int threads = 256, blocks = (N_NODES * HID) / threads;
        node_l2_pool_kernel<<<blocks, threads, 0, stream>>>(h1, s2, cnt, Wl2, Wr2, b2,
                                                            batch, pool, gcnt);
    }
    {   // MLP readout: 32 lanes per graph
        int threads = 256, blocks = (N_GRAPHS * 32) / threads;
        mlp_kernel<<<blocks, threads, 0, stream>>>(pool, gcnt, Wm1, bm1, Wm2, bm2, out);
    }
}

// Round 2
// 789.588 us; speedup vs baseline: 8.4704x; 8.4704x over previous
//
#include <hip/hip_runtime.h>
#include <math.h>

#define N_NODES  100000
#define N_EDGES  1600000
#define N_GRAPHS 1000
#define F_IN     9
#define HID      64
#define SCAN_T   1024

// ---------------------------------------------------------------------------
// Workspace layout (4-byte words):
//   [0,       100000)   deg     (int)   -- zeroed
//   [100000,  200000)   cursor  (int)   -- zeroed
//   [200000,  264000)   pool    (float) -- zeroed  (N_GRAPHS*64)
//   [264000,  364001)   rowptr  (int, N+1)
//   [364001,  1964001)  col     (int, E)
//   [1964004, 2864004)  s1      (float, N*9)
//   [2864004, 9264004)  h1      (float, N*64)
// Zero region = first 264000 words (one memset, ~1 MB).
// ---------------------------------------------------------------------------

__global__ void hist_kernel(const int* __restrict__ ei, int* __restrict__ deg) {
    int e = blockIdx.x * blockDim.x + threadIdx.x;
    if (e >= N_EDGES) return;
    atomicAdd(&deg[ei[N_EDGES + e]], 1);
}

// single-block exclusive scan: deg[0..N) -> rowptr[0..N]
__global__ void scan_kernel(const int* __restrict__ deg, int* __restrict__ rowptr) {
    __shared__ int ts[SCAN_T];
    const int CH = (N_NODES + SCAN_T - 1) / SCAN_T;   // 98
    int t = threadIdx.x;
    int lo = t * CH;
    int hi = lo + CH; if (hi > N_NODES) hi = N_NODES;
    if (lo > N_NODES) lo = N_NODES;
    int s = 0;
    for (int i = lo; i < hi; ++i) s += deg[i];
    ts[t] = s;
    __syncthreads();
    for (int off = 1; off < SCAN_T; off <<= 1) {
        int v = (t >= off) ? ts[t - off] : 0;
        __syncthreads();
        ts[t] += v;
        __syncthreads();
    }
    int run = (t == 0) ? 0 : ts[t - 1];
    for (int i = lo; i < hi; ++i) { rowptr[i] = run; run += deg[i]; }
    if (t == SCAN_T - 1) rowptr[N_NODES] = run;       // = N_EDGES
}

__global__ void fill_kernel(const int* __restrict__ ei,
                            const int* __restrict__ rowptr,
                            int* __restrict__ cursor,
                            int* __restrict__ col) {
    int e = blockIdx.x * blockDim.x + threadIdx.x;
    if (e >= N_EDGES) return;
    int src = ei[e];
    int dst = ei[N_EDGES + e];
    int pos = atomicAdd(&cursor[dst], 1);
    col[rowptr[dst] + pos] = src;
}

// layer-1 neighbor aggregation: thread per (node, in-feature)
__global__ void agg1_kernel(const float* __restrict__ x,
                            const int* __restrict__ rowptr,
                            const int* __restrict__ col,
                            float* __restrict__ s1) {
    int t = blockIdx.x * blockDim.x + threadIdx.x;
    if (t >= N_NODES * F_IN) return;
    int n = t / F_IN;
    int k = t - n * F_IN;
    int lo = rowptr[n], hi = rowptr[n + 1];
    float s = 0.0f;
    for (int i = lo; i < hi; ++i)
        s += x[col[i] * F_IN + k];
    s1[t] = s;
}

// layer-1 dense part: thread per (node, out-feature)
__global__ void node_l1_kernel(const float* __restrict__ x,
                               const float* __restrict__ s1,
                               const int* __restrict__ rowptr,
                               const float* __restrict__ Wl1,
                               const float* __restrict__ Wr1,
                               const float* __restrict__ b1,
                               float* __restrict__ h1) {
    int t = blockIdx.x * blockDim.x + threadIdx.x;
    if (t >= N_NODES * HID) return;
    int n = t >> 6;
    int j = t & 63;
    float inv = 1.0f / fmaxf((float)(rowptr[n + 1] - rowptr[n]), 1.0f);
    float acc = b1[j];
    #pragma unroll
    for (int k = 0; k < F_IN; ++k) {
        acc += s1[n * F_IN + k] * inv * Wl1[k * HID + j];
        acc += x[n * F_IN + k] * Wr1[k * HID + j];
    }
    h1[t] = fmaxf(acc, 0.0f);
}

// fused: layer-2 aggregation (gather) + dense + grouped pool atomics
// block = 256 threads = 4 waves; wave w handles node blockIdx.x*4 + w
__global__ void l2_pool_kernel(const float* __restrict__ h1,
                               const int* __restrict__ rowptr,
                               const int* __restrict__ col,
                               const float* __restrict__ Wl2,
                               const float* __restrict__ Wr2,
                               const float* __restrict__ b2,
                               const int* __restrict__ batch,
                               float* __restrict__ pool) {
    __shared__ float wl[HID * HID];
    __shared__ float wr[HID * HID];
    __shared__ float sa[4][HID];
    __shared__ float sh[4][HID];
    int tid = threadIdx.x;
    int w = tid >> 6;
    int j = tid & 63;
    #pragma unroll
    for (int i = tid; i < HID * HID; i += 256) { wl[i] = Wl2[i]; wr[i] = Wr2[i]; }

    int n = blockIdx.x * 4 + w;
    int lo = rowptr[n], hi = rowptr[n + 1];
    float aggj = 0.0f;
    for (int i = lo; i < hi; ++i)
        aggj += h1[col[i] * HID + j];
    aggj *= 1.0f / fmaxf((float)(hi - lo), 1.0f);
    sa[w][j] = aggj;
    sh[w][j] = h1[n * HID + j];
    __syncthreads();

    float acc = b2[j];
    #pragma unroll 8
    for (int k = 0; k < HID; ++k)
        acc += sa[w][k] * wl[k * HID + j] + sh[w][k] * wr[k * HID + j];

    __syncthreads();                 // everyone done reading sa/sh
    sa[w][j] = acc;                  // reuse sa as h2 staging
    __syncthreads();

    if (w == 0) {                    // grouped pool atomics (batch is sorted)
        int base = blockIdx.x * 4;
        int g0 = batch[base + 0], g1 = batch[base + 1];
        int g2 = batch[base + 2], g3 = batch[base + 3];
        int cur = g0;
        float v = sa[0][j];
        if (g1 == cur) v += sa[1][j];
        else { atomicAdd(&pool[cur * HID + j], v); cur = g1; v = sa[1][j]; }
        if (g2 == cur) v += sa[2][j];
        else { atomicAdd(&pool[cur * HID + j], v); cur = g2; v = sa[2][j]; }
        if (g3 == cur) v += sa[3][j];
        else { atomicAdd(&pool[cur * HID + j], v); cur = g3; v = sa[3][j]; }
        atomicAdd(&pool[cur * HID + j], v);
    }
}

// readout: one wave (64 lanes) per graph; node count via binary search on batch
__global__ void mlp_kernel(const float* __restrict__ pool,
                           const int* __restrict__ batch,
                           const float* __restrict__ Wm1,
                           const float* __restrict__ bm1,
                           const float* __restrict__ Wm2,
                           const float* __restrict__ bm2,
                           float* __restrict__ out) {
    __shared__ float sx[4][HID];
    int t = blockIdx.x * blockDim.x + threadIdx.x;
    int g = t >> 6;
    int j = t & 63;
    int w = threadIdx.x >> 6;
    if (g >= N_GRAPHS) return;
    // lower_bound(batch, g) and lower_bound(batch, g+1)
    int lo = 0, hi = N_NODES;
    while (lo < hi) { int m = (lo + hi) >> 1; if (batch[m] < g) lo = m + 1; else hi = m; }
    int start = lo;
    lo = 0; hi = N_NODES;
    while (lo < hi) { int m = (lo + hi) >> 1; if (batch[m] < g + 1) lo = m + 1; else hi = m; }
    int cntg = lo - start;
    float inv = 1.0f / fmaxf((float)cntg, 1.0f);
    sx[w][j] = pool[g * HID + j] * inv;   // wave-local staging (lockstep wave, no barrier)
    if (j < 32) {
        float a = bm1[j];
        #pragma unroll 8
        for (int k = 0; k < HID; ++k)
            a += sx[w][k] * Wm1[k * 32 + j];
        float r = fmaxf(a, 0.0f) * Wm2[j];
        #pragma unroll
        for (int off = 16; off > 0; off >>= 1)
            r += __shfl_down(r, off, 32);
        if (j == 0)
            out[g] = 1.0f / (1.0f + expf(-(r + bm2[0])));
    }
}

extern "C" void kernel_launch(void* const* d_in, const int* in_sizes, int n_in,
                              void* d_out, int out_size, void* d_ws, size_t ws_size,
                              hipStream_t stream) {
    const float* x    = (const float*)d_in[0];
    const int*   ei   = (const int*)d_in[1];
    // d_in[2] = edge_attr (all zeros, unused)
    const int*   batch= (const int*)d_in[3];
    const float* Wl1  = (const float*)d_in[4];
    const float* Wr1  = (const float*)d_in[5];
    const float* b1   = (const float*)d_in[6];
    const float* Wl2  = (const float*)d_in[7];
    const float* Wr2  = (const float*)d_in[8];
    const float* b2   = (const float*)d_in[9];
    const float* Wm1  = (const float*)d_in[10];
    const float* bm1  = (const float*)d_in[11];
    const float* Wm2  = (const float*)d_in[12];
    const float* bm2  = (const float*)d_in[13];
    float* out = (float*)d_out;

    int*   wsi    = (int*)d_ws;
    float* wsf    = (float*)d_ws;
    int*   deg    = wsi;
    int*   cursor = wsi + 100000;
    float* pool   = wsf + 200000;
    int*   rowptr = wsi + 264000;
    int*   col    = wsi + 364001;
    float* s1     = wsf + 1964004;
    float* h1     = wsf + 2864004;

    hipMemsetAsync(d_ws, 0, 264000 * sizeof(int), stream);   // deg+cursor+pool

    {   int th = 256, bl = (N_EDGES + th - 1) / th;
        hist_kernel<<<bl, th, 0, stream>>>(ei, deg);
    }
    scan_kernel<<<1, SCAN_T, 0, stream>>>(deg, rowptr);
    {   int th = 256, bl = (N_EDGES + th - 1) / th;
        fill_kernel<<<bl, th, 0, stream>>>(ei, rowptr, cursor, col);
    }
    {   int th = 256, bl = (N_NODES * F_IN + th - 1) / th;
        agg1_kernel<<<bl, th, 0, stream>>>(x, rowptr, col, s1);
    }
    {   int th = 256, bl = (N_NODES * HID) / th;
        node_l1_kernel<<<bl, th, 0, stream>>>(x, s1, rowptr, Wl1, Wr1, b1, h1);
    }
    {   int th = 256, bl = N_NODES / 4;   // 25000 blocks, 4 nodes each
        l2_pool_kernel<<<bl, th, 0, stream>>>(h1, rowptr, col, Wl2, Wr2, b2, batch, pool);
    }
    {   int th = 256, bl = (N_GRAPHS * 64) / th;
        mlp_kernel<<<bl, th, 0, stream>>>(pool, batch, Wm1, bm1, Wm2, bm2, out);
    }
}

// Round 3
// 552.963 us; speedup vs baseline: 12.0951x; 1.4279x over previous
//
#include <hip/hip_runtime.h>
#include <math.h>

#define N_NODES  100000
#define N_EDGES  1600000
#define N_GRAPHS 1000
#define F_IN     9
#define HID      64
#define SCAN_T   1024

// ---------------------------------------------------------------------------
// Workspace layout (4-byte words):
//   [0,       100000)   deg     (int)   -- zeroed
//   [100000,  200000)   cursor  (int)   -- zeroed
//   [200000,  264000)   pool    (float) -- zeroed  (N_GRAPHS*64)
//   [264000,  364001)   rowptr  (int, N+1)
//   [364001,  1964001)  col     (int, E)
//   [1964004, 8364004)  h1      (float, N*64)
//   [8364004, 14764004) y       (float, N*64)   = h1 @ Wl2
//     x16 (N*16) and s16 (N*16) alias the y region: both are dead before
//     gemm2 writes y (pad->agg1->node_l1 all complete first).
// Total 14,764,004 words = 59.1 MB. Zero region = first 264000 words.
// ---------------------------------------------------------------------------

__global__ void hist_kernel(const int* __restrict__ ei, int* __restrict__ deg) {
    int e = blockIdx.x * blockDim.x + threadIdx.x;
    if (e >= N_EDGES) return;
    atomicAdd(&deg[ei[N_EDGES + e]], 1);
}

// single-block exclusive scan: deg[0..N) -> rowptr[0..N]
__global__ void scan_kernel(const int* __restrict__ deg, int* __restrict__ rowptr) {
    __shared__ int ts[SCAN_T];
    const int CH = (N_NODES + SCAN_T - 1) / SCAN_T;   // 98
    int t = threadIdx.x;
    int lo = t * CH;
    int hi = lo + CH; if (hi > N_NODES) hi = N_NODES;
    if (lo > N_NODES) lo = N_NODES;
    int s = 0;
    for (int i = lo; i < hi; ++i) s += deg[i];
    ts[t] = s;
    __syncthreads();
    for (int off = 1; off < SCAN_T; off <<= 1) {
        int v = (t >= off) ? ts[t - off] : 0;
        __syncthreads();
        ts[t] += v;
        __syncthreads();
    }
    int run = (t == 0) ? 0 : ts[t - 1];
    for (int i = lo; i < hi; ++i) { rowptr[i] = run; run += deg[i]; }
    if (t == SCAN_T - 1) rowptr[N_NODES] = run;       // = N_EDGES
}

__global__ void fill_kernel(const int* __restrict__ ei,
                            const int* __restrict__ rowptr,
                            int* __restrict__ cursor,
                            int* __restrict__ col) {
    int e = blockIdx.x * blockDim.x + threadIdx.x;
    if (e >= N_EDGES) return;
    int src = ei[e];
    int dst = ei[N_EDGES + e];
    int pos = atomicAdd(&cursor[dst], 1);
    col[rowptr[dst] + pos] = src;
}

// pad x [N,9] -> x16 [N,16] (zeros in cols 9..15) so gathers are float4-clean
__global__ void pad_x_kernel(const float* __restrict__ x, float* __restrict__ x16) {
    int t = blockIdx.x * blockDim.x + threadIdx.x;
    if (t >= N_NODES * 16) return;
    int n = t >> 4, k = t & 15;
    x16[t] = (k < F_IN) ? x[n * F_IN + k] : 0.0f;
}

// layer-1 gather: 4 threads per node, float4 each, unroll-4 for MLP
__global__ void agg1_kernel(const float* __restrict__ x16,
                            const int* __restrict__ rowptr,
                            const int* __restrict__ col,
                            float* __restrict__ s16) {
    int t = blockIdx.x * blockDim.x + threadIdx.x;
    if (t >= N_NODES * 4) return;
    int n = t >> 2, q4 = (t & 3) * 4;
    int lo = rowptr[n], hi = rowptr[n + 1];
    float4 a = make_float4(0.f, 0.f, 0.f, 0.f);
    #pragma unroll 4
    for (int i = lo; i < hi; ++i) {
        int c = col[i];
        float4 v = *reinterpret_cast<const float4*>(&x16[(size_t)c * 16 + q4]);
        a.x += v.x; a.y += v.y; a.z += v.z; a.w += v.w;
    }
    *reinterpret_cast<float4*>(&s16[(size_t)n * 16 + q4]) = a;
}

// layer-1 dense: thread per (node, out-feature); s16/x reads are wave-uniform
__global__ void node_l1_kernel(const float* __restrict__ x,
                               const float* __restrict__ s16,
                               const int* __restrict__ rowptr,
                               const float* __restrict__ Wl1,
                               const float* __restrict__ Wr1,
                               const float* __restrict__ b1,
                               float* __restrict__ h1) {
    int t = blockIdx.x * blockDim.x + threadIdx.x;
    if (t >= N_NODES * HID) return;
    int n = t >> 6;
    int j = t & 63;
    float inv = 1.0f / fmaxf((float)(rowptr[n + 1] - rowptr[n]), 1.0f);
    float acc = b1[j];
    #pragma unroll
    for (int k = 0; k < F_IN; ++k) {
        acc += s16[n * 16 + k] * inv * Wl1[k * HID + j];
        acc += x[n * F_IN + k] * Wr1[k * HID + j];
    }
    h1[t] = fmaxf(acc, 0.0f);
}

// register-tiled GEMM: y = h1 @ Wl2 ; z = h1 @ Wr2 + b2 (z -> pool atomics)
// block = 256 threads, tile = 64 nodes x 128 cols (cols 0-63 -> y, 64-127 -> z)
__global__ __launch_bounds__(256) void gemm2_kernel(const float* __restrict__ h1,
                                                    const float* __restrict__ Wl2,
                                                    const float* __restrict__ Wr2,
                                                    const float* __restrict__ b2,
                                                    const int* __restrict__ batch,
                                                    float* __restrict__ y,
                                                    float* __restrict__ pool) {
    __shared__ float wsw[HID * 128];     // combined [k][ Wl2 | Wr2 ]
    __shared__ float hs[64 * 65];        // 64 nodes x 64 k, +1 pad
    int tid = threadIdx.x;
    int n0 = blockIdx.x * 64;
    for (int i = tid; i < HID * HID; i += 256) {
        int k = i >> 6, j = i & 63;
        wsw[k * 128 + j]      = Wl2[i];
        wsw[k * 128 + 64 + j] = Wr2[i];
    }
    for (int i = tid; i < 64 * HID; i += 256) {
        int r = i >> 6, k = i & 63;
        int n = n0 + r;
        hs[r * 65 + k] = (n < N_NODES) ? h1[(size_t)n * HID + k] : 0.0f;
    }
    __syncthreads();

    int tm = tid >> 4, tn = tid & 15;    // 16 row-groups x 16 col-groups
    int r0 = tm * 4, c0 = tn * 8;
    float acc[4][8];
    #pragma unroll
    for (int r = 0; r < 4; ++r)
        #pragma unroll
        for (int c = 0; c < 8; ++c) acc[r][c] = 0.0f;

    #pragma unroll 4
    for (int k = 0; k < HID; ++k) {
        float a0 = hs[(r0 + 0) * 65 + k];
        float a1 = hs[(r0 + 1) * 65 + k];
        float a2 = hs[(r0 + 2) * 65 + k];
        float a3 = hs[(r0 + 3) * 65 + k];
        const float* wrow = &wsw[k * 128 + c0];
        #pragma unroll
        for (int c = 0; c < 8; ++c) {
            float w = wrow[c];
            acc[0][c] += a0 * w;
            acc[1][c] += a1 * w;
            acc[2][c] += a2 * w;
            acc[3][c] += a3 * w;
        }
    }

    if (tn < 8) {                        // y half: store
        #pragma unroll
        for (int r = 0; r < 4; ++r) {
            int n = n0 + r0 + r;
            if (n < N_NODES) {
                float4* dst = (float4*)&y[(size_t)n * HID + c0];
                dst[0] = make_float4(acc[r][0], acc[r][1], acc[r][2], acc[r][3]);
                dst[1] = make_float4(acc[r][4], acc[r][5], acc[r][6], acc[r][7]);
            }
        }
    }
    __syncthreads();                     // hs no longer needed as acts
    if (tn >= 8) {                       // z half: stage into hs
        int zc = c0 - 64;
        #pragma unroll
        for (int r = 0; r < 4; ++r) {
            int n = n0 + r0 + r;
            bool ok = (n < N_NODES);
            #pragma unroll
            for (int c = 0; c < 8; ++c)
                hs[(r0 + r) * 65 + zc + c] = ok ? (acc[r][c] + b2[zc + c]) : 0.0f;
        }
    }
    __syncthreads();
    if (tid < HID) {                     // grouped pool atomics (batch sorted)
        int j = tid;
        int cur = batch[(n0 < N_NODES) ? n0 : (N_NODES - 1)];
        float v = hs[0 * 65 + j];
        for (int r = 1; r < 64; ++r) {
            int n = n0 + r;
            int g = batch[(n < N_NODES) ? n : (N_NODES - 1)];
            float val = hs[r * 65 + j];
            if (g == cur) v += val;
            else { atomicAdd(&pool[cur * HID + j], v); cur = g; v = val; }
        }
        atomicAdd(&pool[cur * HID + j], v);
    }
}

// layer-2 gather on y + pool: wave per node; lanes = 4 edge-slots x 16 f4-groups
__global__ __launch_bounds__(1024) void gather2_kernel(const float* __restrict__ y,
                                                       const int* __restrict__ rowptr,
                                                       const int* __restrict__ col,
                                                       const int* __restrict__ batch,
                                                       float* __restrict__ pool) {
    __shared__ float sh[16][HID];
    int w = threadIdx.x >> 6;
    int lane = threadIdx.x & 63;
    int q = lane >> 4;
    int f4 = (lane & 15) * 4;
    int n = blockIdx.x * 16 + w;
    int lo = rowptr[n], hi = rowptr[n + 1];
    float4 acc = make_float4(0.f, 0.f, 0.f, 0.f);
    #pragma unroll 2
    for (int i = lo + q; i < hi; i += 4) {
        int c = col[i];
        float4 v = *reinterpret_cast<const float4*>(&y[(size_t)c * HID + f4]);
        acc.x += v.x; acc.y += v.y; acc.z += v.z; acc.w += v.w;
    }
    // reduce across the 4 edge-slot groups (lane bits 4 and 5)
    acc.x += __shfl_xor(acc.x, 16, 64);
    acc.y += __shfl_xor(acc.y, 16, 64);
    acc.z += __shfl_xor(acc.z, 16, 64);
    acc.w += __shfl_xor(acc.w, 16, 64);
    acc.x += __shfl_xor(acc.x, 32, 64);
    acc.y += __shfl_xor(acc.y, 32, 64);
    acc.z += __shfl_xor(acc.z, 32, 64);
    acc.w += __shfl_xor(acc.w, 32, 64);
    float inv = 1.0f / fmaxf((float)(hi - lo), 1.0f);
    if (lane < 16) {
        float4 r = make_float4(acc.x * inv, acc.y * inv, acc.z * inv, acc.w * inv);
        *reinterpret_cast<float4*>(&sh[w][f4]) = r;
    }
    __syncthreads();
    if (threadIdx.x < HID) {             // grouped pool atomics for 16 nodes
        int j = threadIdx.x;
        int base = blockIdx.x * 16;
        int cur = batch[base];
        float v = sh[0][j];
        for (int r = 1; r < 16; ++r) {
            int g = batch[base + r];
            float val = sh[r][j];
            if (g == cur) v += val;
            else { atomicAdd(&pool[cur * HID + j], v); cur = g; v = val; }
        }
        atomicAdd(&pool[cur * HID + j], v);
    }
}

// readout: one wave (64 lanes) per graph; node count via binary search on batch
__global__ void mlp_kernel(const float* __restrict__ pool,
                           const int* __restrict__ batch,
                           const float* __restrict__ Wm1,
                           const float* __restrict__ bm1,
                           const float* __restrict__ Wm2,
                           const float* __restrict__ bm2,
                           float* __restrict__ out) {
    __shared__ float sx[4][HID];
    int t = blockIdx.x * blockDim.x + threadIdx.x;
    int g = t >> 6;
    int j = t & 63;
    int w = threadIdx.x >> 6;
    if (g >= N_GRAPHS) return;
    int lo = 0, hi = N_NODES;
    while (lo < hi) { int m = (lo + hi) >> 1; if (batch[m] < g) lo = m + 1; else hi = m; }
    int start = lo;
    lo = 0; hi = N_NODES;
    while (lo < hi) { int m = (lo + hi) >> 1; if (batch[m] < g + 1) lo = m + 1; else hi = m; }
    int cntg = lo - start;
    float inv = 1.0f / fmaxf((float)cntg, 1.0f);
    sx[w][j] = pool[g * HID + j] * inv;
    if (j < 32) {
        float a = bm1[j];
        #pragma unroll 8
        for (int k = 0; k < HID; ++k)
            a += sx[w][k] * Wm1[k * 32 + j];
        float r = fmaxf(a, 0.0f) * Wm2[j];
        #pragma unroll
        for (int off = 16; off > 0; off >>= 1)
            r += __shfl_down(r, off, 32);
        if (j == 0)
            out[g] = 1.0f / (1.0f + expf(-(r + bm2[0])));
    }
}

extern "C" void kernel_launch(void* const* d_in, const int* in_sizes, int n_in,
                              void* d_out, int out_size, void* d_ws, size_t ws_size,
                              hipStream_t stream) {
    const float* x    = (const float*)d_in[0];
    const int*   ei   = (const int*)d_in[1];
    // d_in[2] = edge_attr (all zeros, unused)
    const int*   batch= (const int*)d_in[3];
    const float* Wl1  = (const float*)d_in[4];
    const float* Wr1  = (const float*)d_in[5];
    const float* b1   = (const float*)d_in[6];
    const float* Wl2  = (const float*)d_in[7];
    const float* Wr2  = (const float*)d_in[8];
    const float* b2   = (const float*)d_in[9];
    const float* Wm1  = (const float*)d_in[10];
    const float* bm1  = (const float*)d_in[11];
    const float* Wm2  = (const float*)d_in[12];
    const float* bm2  = (const float*)d_in[13];
    float* out = (float*)d_out;

    int*   wsi    = (int*)d_ws;
    float* wsf    = (float*)d_ws;
    int*   deg    = wsi;
    int*   cursor = wsi + 100000;
    float* pool   = wsf + 200000;
    int*   rowptr = wsi + 264000;
    int*   col    = wsi + 364001;
    float* h1     = wsf + 1964004;
    float* y      = wsf + 8364004;
    float* x16    = wsf + 8364004;               // aliases y (dead before gemm2)
    float* s16    = wsf + 9964004;               // aliases y (dead before gemm2)

    hipMemsetAsync(d_ws, 0, 264000 * sizeof(int), stream);   // deg+cursor+pool

    {   int th = 256, bl = (N_EDGES + th - 1) / th;
        hist_kernel<<<bl, th, 0, stream>>>(ei, deg);
    }
    scan_kernel<<<1, SCAN_T, 0, stream>>>(deg, rowptr);
    {   int th = 256, bl = (N_EDGES + th - 1) / th;
        fill_kernel<<<bl, th, 0, stream>>>(ei, rowptr, cursor, col);
    }
    {   int th = 256, bl = (N_NODES * 16 + th - 1) / th;
        pad_x_kernel<<<bl, th, 0, stream>>>(x, x16);
    }
    {   int th = 256, bl = (N_NODES * 4 + th - 1) / th;
        agg1_kernel<<<bl, th, 0, stream>>>(x16, rowptr, col, s16);
    }
    {   int th = 256, bl = (N_NODES * HID) / th;
        node_l1_kernel<<<bl, th, 0, stream>>>(x, s16, rowptr, Wl1, Wr1, b1, h1);
    }
    {   int th = 256, bl = (N_NODES + 63) / 64;   // 1563 blocks, 64 nodes each
        gemm2_kernel<<<bl, th, 0, stream>>>(h1, Wl2, Wr2, b2, batch, y, pool);
    }
    {   int th = 1024, bl = N_NODES / 16;         // 6250 blocks, 16 nodes each
        gather2_kernel<<<bl, th, 0, stream>>>(y, rowptr, col, batch, pool);
    }
    {   int th = 256, bl = (N_GRAPHS * 64) / th;
        mlp_kernel<<<bl, th, 0, stream>>>(pool, batch, Wm1, bm1, Wm2, bm2, out);
    }
}

// Round 4
// 392.975 us; speedup vs baseline: 17.0193x; 1.4071x over previous
//
#include <hip/hip_runtime.h>
#include <math.h>

#define N_NODES  100000
#define N_EDGES  1600000
#define N_GRAPHS 1000
#define F_IN     9
#define HID      64
#define NB_SCAN  391   // ceil(N_NODES / 256)

// ---------------------------------------------------------------------------
// Workspace layout (4-byte words):
//   [0,       100000)   deg     (int)   -- zeroed
//   [100000,  200000)   cursor  (int)   -- zeroed
//   [200000,  264000)   pool    (float) -- zeroed  (N_GRAPHS*64)
//   [264000,  364001)   rowptr  (int, N+1)
//   [364004,  1964004)  col     (int, E)
//   [1964004, 8364004)  h1      (float, N*64)
//   [8364004, 14764004) y       (float, N*64)   = h1 @ Wl2
//     x16 (N*16) and s16 (N*16) alias the y region: both are dead before
//     gemm2 writes y (pad->agg1->node_l1 all complete first).
//   [14764004,14764404) bsum    (int, NB_SCAN)
// Zero region = first 264000 words.
// ---------------------------------------------------------------------------

__global__ void hist_kernel(const int* __restrict__ ei, int* __restrict__ deg) {
    int e = blockIdx.x * blockDim.x + threadIdx.x;
    if (e >= N_EDGES) return;
    atomicAdd(&deg[ei[N_EDGES + e]], 1);
}

// scan phase 1: per-block (256 elems) sums
__global__ void scan1_kernel(const int* __restrict__ deg, int* __restrict__ bsum) {
    int i = blockIdx.x * 256 + threadIdx.x;
    int v = (i < N_NODES) ? deg[i] : 0;
    #pragma unroll
    for (int off = 1; off < 64; off <<= 1) v += __shfl_xor(v, off, 64);
    __shared__ int ws[4];
    if ((threadIdx.x & 63) == 0) ws[threadIdx.x >> 6] = v;
    __syncthreads();
    if (threadIdx.x == 0) bsum[blockIdx.x] = ws[0] + ws[1] + ws[2] + ws[3];
}

// scan phase 2: exclusive scan of the NB_SCAN block sums (in place)
__global__ void scan2_kernel(int* __restrict__ bsum) {
    __shared__ int ts[512];
    int t = threadIdx.x;
    ts[t] = (t < NB_SCAN) ? bsum[t] : 0;
    __syncthreads();
    for (int off = 1; off < 512; off <<= 1) {
        int v = (t >= off) ? ts[t - off] : 0;
        __syncthreads();
        ts[t] += v;
        __syncthreads();
    }
    if (t < NB_SCAN) bsum[t] = (t == 0) ? 0 : ts[t - 1];
}

// scan phase 3: in-block exclusive scan + block offset -> rowptr
__global__ void scan3_kernel(const int* __restrict__ deg,
                             const int* __restrict__ bsum,
                             int* __restrict__ rowptr) {
    int i = blockIdx.x * 256 + threadIdx.x;
    int v = (i < N_NODES) ? deg[i] : 0;
    int lane = threadIdx.x & 63;
    int wid = threadIdx.x >> 6;
    int s = v;
    #pragma unroll
    for (int off = 1; off < 64; off <<= 1) {
        int u = __shfl_up(s, off, 64);
        if (lane >= off) s += u;
    }
    __shared__ int wsum[4];
    if (lane == 63) wsum[wid] = s;
    __syncthreads();
    int add = 0;
    for (int w = 0; w < wid; ++w) add += wsum[w];
    if (i < N_NODES) rowptr[i] = s - v + add + bsum[blockIdx.x];
    if (blockIdx.x == 0 && threadIdx.x == 0) rowptr[N_NODES] = N_EDGES;
}

__global__ void fill_kernel(const int* __restrict__ ei,
                            const int* __restrict__ rowptr,
                            int* __restrict__ cursor,
                            int* __restrict__ col) {
    int e = blockIdx.x * blockDim.x + threadIdx.x;
    if (e >= N_EDGES) return;
    int src = ei[e];
    int dst = ei[N_EDGES + e];
    int pos = atomicAdd(&cursor[dst], 1);
    col[rowptr[dst] + pos] = src;
}

// pad x [N,9] -> x16 [N,16] (zeros in cols 9..15) so gathers are float4-clean
__global__ void pad_x_kernel(const float* __restrict__ x, float* __restrict__ x16) {
    int t = blockIdx.x * blockDim.x + threadIdx.x;
    if (t >= N_NODES * 16) return;
    int n = t >> 4, k = t & 15;
    x16[t] = (k < F_IN) ? x[n * F_IN + k] : 0.0f;
}

// layer-1 gather: 4 threads per node, float4 each
__global__ void agg1_kernel(const float* __restrict__ x16,
                            const int* __restrict__ rowptr,
                            const int* __restrict__ col,
                            float* __restrict__ s16) {
    int t = blockIdx.x * blockDim.x + threadIdx.x;
    if (t >= N_NODES * 4) return;
    int n = t >> 2, q4 = (t & 3) * 4;
    int lo = rowptr[n], hi = rowptr[n + 1];
    float4 a = make_float4(0.f, 0.f, 0.f, 0.f);
    #pragma unroll 4
    for (int i = lo; i < hi; ++i) {
        int c = col[i];
        float4 v = *reinterpret_cast<const float4*>(&x16[(size_t)c * 16 + q4]);
        a.x += v.x; a.y += v.y; a.z += v.z; a.w += v.w;
    }
    *reinterpret_cast<float4*>(&s16[(size_t)n * 16 + q4]) = a;
}

// layer-1 dense: thread per (node, out-feature)
__global__ void node_l1_kernel(const float* __restrict__ x,
                               const float* __restrict__ s16,
                               const int* __restrict__ rowptr,
                               const float* __restrict__ Wl1,
                               const float* __restrict__ Wr1,
                               const float* __restrict__ b1,
                               float* __restrict__ h1) {
    int t = blockIdx.x * blockDim.x + threadIdx.x;
    if (t >= N_NODES * HID) return;
    int n = t >> 6;
    int j = t & 63;
    float inv = 1.0f / fmaxf((float)(rowptr[n + 1] - rowptr[n]), 1.0f);
    float acc = b1[j];
    #pragma unroll
    for (int k = 0; k < F_IN; ++k) {
        acc += s16[n * 16 + k] * inv * Wl1[k * HID + j];
        acc += x[n * F_IN + k] * Wr1[k * HID + j];
    }
    h1[t] = fmaxf(acc, 0.0f);
}

// register-tiled GEMM: y = h1 @ Wl2 ; z = h1 @ Wr2 + b2 (z -> pool atomics)
__global__ __launch_bounds__(256) void gemm2_kernel(const float* __restrict__ h1,
                                                    const float* __restrict__ Wl2,
                                                    const float* __restrict__ Wr2,
                                                    const float* __restrict__ b2,
                                                    const int* __restrict__ batch,
                                                    float* __restrict__ y,
                                                    float* __restrict__ pool) {
    __shared__ float wsw[HID * 128];     // combined [k][ Wl2 | Wr2 ]
    __shared__ float hs[64 * 65];        // 64 nodes x 64 k, +1 pad
    int tid = threadIdx.x;
    int n0 = blockIdx.x * 64;
    for (int i = tid; i < HID * HID; i += 256) {
        int k = i >> 6, j = i & 63;
        wsw[k * 128 + j]      = Wl2[i];
        wsw[k * 128 + 64 + j] = Wr2[i];
    }
    for (int i = tid; i < 64 * HID; i += 256) {
        int r = i >> 6, k = i & 63;
        int n = n0 + r;
        hs[r * 65 + k] = (n < N_NODES) ? h1[(size_t)n * HID + k] : 0.0f;
    }
    __syncthreads();

    int tm = tid >> 4, tn = tid & 15;
    int r0 = tm * 4, c0 = tn * 8;
    float acc[4][8];
    #pragma unroll
    for (int r = 0; r < 4; ++r)
        #pragma unroll
        for (int c = 0; c < 8; ++c) acc[r][c] = 0.0f;

    #pragma unroll 4
    for (int k = 0; k < HID; ++k) {
        float a0 = hs[(r0 + 0) * 65 + k];
        float a1 = hs[(r0 + 1) * 65 + k];
        float a2 = hs[(r0 + 2) * 65 + k];
        float a3 = hs[(r0 + 3) * 65 + k];
        const float* wrow = &wsw[k * 128 + c0];
        #pragma unroll
        for (int c = 0; c < 8; ++c) {
            float w = wrow[c];
            acc[0][c] += a0 * w;
            acc[1][c] += a1 * w;
            acc[2][c] += a2 * w;
            acc[3][c] += a3 * w;
        }
    }

    if (tn < 8) {                        // y half
        #pragma unroll
        for (int r = 0; r < 4; ++r) {
            int n = n0 + r0 + r;
            if (n < N_NODES) {
                float4* dst = (float4*)&y[(size_t)n * HID + c0];
                dst[0] = make_float4(acc[r][0], acc[r][1], acc[r][2], acc[r][3]);
                dst[1] = make_float4(acc[r][4], acc[r][5], acc[r][6], acc[r][7]);
            }
        }
    }
    __syncthreads();
    if (tn >= 8) {                       // z half -> stage into hs
        int zc = c0 - 64;
        #pragma unroll
        for (int r = 0; r < 4; ++r) {
            int n = n0 + r0 + r;
            bool ok = (n < N_NODES);
            #pragma unroll
            for (int c = 0; c < 8; ++c)
                hs[(r0 + r) * 65 + zc + c] = ok ? (acc[r][c] + b2[zc + c]) : 0.0f;
        }
    }
    __syncthreads();
    if (tid < HID) {                     // grouped pool atomics (batch sorted)
        int j = tid;
        int cur = batch[(n0 < N_NODES) ? n0 : (N_NODES - 1)];
        float v = hs[0 * 65 + j];
        for (int r = 1; r < 64; ++r) {
            int n = n0 + r;
            int g = batch[(n < N_NODES) ? n : (N_NODES - 1)];
            float val = hs[r * 65 + j];
            if (g == cur) v += val;
            else { atomicAdd(&pool[cur * HID + j], v); cur = g; v = val; }
        }
        atomicAdd(&pool[cur * HID + j], v);
    }
}

// layer-2 gather on y + pool: wave per node; lanes = 4 edge-slots x 16 f4-groups
__global__ __launch_bounds__(1024) void gather2_kernel(const float* __restrict__ y,
                                                       const int* __restrict__ rowptr,
                                                       const int* __restrict__ col,
                                                       const int* __restrict__ batch,
                                                       float* __restrict__ pool) {
    __shared__ float sh[16][HID];
    int w = threadIdx.x >> 6;
    int lane = threadIdx.x & 63;
    int q = lane >> 4;
    int f4 = (lane & 15) * 4;
    int n = blockIdx.x * 16 + w;
    int lo = rowptr[n], hi = rowptr[n + 1];
    float4 acc = make_float4(0.f, 0.f, 0.f, 0.f);
    #pragma unroll 2
    for (int i = lo + q; i < hi; i += 4) {
        int c = col[i];
        float4 v = *reinterpret_cast<const float4*>(&y[(size_t)c * HID + f4]);
        acc.x += v.x; acc.y += v.y; acc.z += v.z; acc.w += v.w;
    }
    acc.x += __shfl_xor(acc.x, 16, 64);
    acc.y += __shfl_xor(acc.y, 16, 64);
    acc.z += __shfl_xor(acc.z, 16, 64);
    acc.w += __shfl_xor(acc.w, 16, 64);
    acc.x += __shfl_xor(acc.x, 32, 64);
    acc.y += __shfl_xor(acc.y, 32, 64);
    acc.z += __shfl_xor(acc.z, 32, 64);
    acc.w += __shfl_xor(acc.w, 32, 64);
    float inv = 1.0f / fmaxf((float)(hi - lo), 1.0f);
    if (lane < 16) {
        float4 r = make_float4(acc.x * inv, acc.y * inv, acc.z * inv, acc.w * inv);
        *reinterpret_cast<float4*>(&sh[w][f4]) = r;
    }
    __syncthreads();
    if (threadIdx.x < HID) {
        int j = threadIdx.x;
        int base = blockIdx.x * 16;
        int cur = batch[base];
        float v = sh[0][j];
        for (int r = 1; r < 16; ++r) {
            int g = batch[base + r];
            float val = sh[r][j];
            if (g == cur) v += val;
            else { atomicAdd(&pool[cur * HID + j], v); cur = g; v = val; }
        }
        atomicAdd(&pool[cur * HID + j], v);
    }
}

// readout: one wave per graph; node count via binary search on batch
__global__ void mlp_kernel(const float* __restrict__ pool,
                           const int* __restrict__ batch,
                           const float* __restrict__ Wm1,
                           const float* __restrict__ bm1,
                           const float* __restrict__ Wm2,
                           const float* __restrict__ bm2,
                           float* __restrict__ out) {
    __shared__ float sx[4][HID];
    int t = blockIdx.x * blockDim.x + threadIdx.x;
    int g = t >> 6;
    int j = t & 63;
    int w = threadIdx.x >> 6;
    if (g >= N_GRAPHS) return;
    int lo = 0, hi = N_NODES;
    while (lo < hi) { int m = (lo + hi) >> 1; if (batch[m] < g) lo = m + 1; else hi = m; }
    int start = lo;
    lo = 0; hi = N_NODES;
    while (lo < hi) { int m = (lo + hi) >> 1; if (batch[m] < g + 1) lo = m + 1; else hi = m; }
    int cntg = lo - start;
    float inv = 1.0f / fmaxf((float)cntg, 1.0f);
    sx[w][j] = pool[g * HID + j] * inv;
    if (j < 32) {
        float a = bm1[j];
        #pragma unroll 8
        for (int k = 0; k < HID; ++k)
            a += sx[w][k] * Wm1[k * 32 + j];
        float r = fmaxf(a, 0.0f) * Wm2[j];
        #pragma unroll
        for (int off = 16; off > 0; off >>= 1)
            r += __shfl_down(r, off, 32);
        if (j == 0)
            out[g] = 1.0f / (1.0f + expf(-(r + bm2[0])));
    }
}

extern "C" void kernel_launch(void* const* d_in, const int* in_sizes, int n_in,
                              void* d_out, int out_size, void* d_ws, size_t ws_size,
                              hipStream_t stream) {
    const float* x    = (const float*)d_in[0];
    const int*   ei   = (const int*)d_in[1];
    // d_in[2] = edge_attr (all zeros, unused)
    const int*   batch= (const int*)d_in[3];
    const float* Wl1  = (const float*)d_in[4];
    const float* Wr1  = (const float*)d_in[5];
    const float* b1   = (const float*)d_in[6];
    const float* Wl2  = (const float*)d_in[7];
    const float* Wr2  = (const float*)d_in[8];
    const float* b2   = (const float*)d_in[9];
    const float* Wm1  = (const float*)d_in[10];
    const float* bm1  = (const float*)d_in[11];
    const float* Wm2  = (const float*)d_in[12];
    const float* bm2  = (const float*)d_in[13];
    float* out = (float*)d_out;

    int*   wsi    = (int*)d_ws;
    float* wsf    = (float*)d_ws;
    int*   deg    = wsi;
    int*   cursor = wsi + 100000;
    float* pool   = wsf + 200000;
    int*   rowptr = wsi + 264000;
    int*   col    = wsi + 364004;
    float* h1     = wsf + 1964004;
    float* y      = wsf + 8364004;
    float* x16    = wsf + 8364004;               // aliases y (dead before gemm2)
    float* s16    = wsf + 9964004;               // aliases y (dead before gemm2)
    int*   bsum   = wsi + 14764004;

    hipMemsetAsync(d_ws, 0, 264000 * sizeof(int), stream);   // deg+cursor+pool

    {   int th = 256, bl = (N_EDGES + th - 1) / th;
        hist_kernel<<<bl, th, 0, stream>>>(ei, deg);
    }
    scan1_kernel<<<NB_SCAN, 256, 0, stream>>>(deg, bsum);
    scan2_kernel<<<1, 512, 0, stream>>>(bsum);
    scan3_kernel<<<NB_SCAN, 256, 0, stream>>>(deg, bsum, rowptr);
    {   int th = 256, bl = (N_EDGES + th - 1) / th;
        fill_kernel<<<bl, th, 0, stream>>>(ei, rowptr, cursor, col);
    }
    {   int th = 256, bl = (N_NODES * 16 + th - 1) / th;
        pad_x_kernel<<<bl, th, 0, stream>>>(x, x16);
    }
    {   int th = 256, bl = (N_NODES * 4 + th - 1) / th;
        agg1_kernel<<<bl, th, 0, stream>>>(x16, rowptr, col, s16);
    }
    {   int th = 256, bl = (N_NODES * HID) / th;
        node_l1_kernel<<<bl, th, 0, stream>>>(x, s16, rowptr, Wl1, Wr1, b1, h1);
    }
    {   int th = 256, bl = (N_NODES + 63) / 64;
        gemm2_kernel<<<bl, th, 0, stream>>>(h1, Wl2, Wr2, b2, batch, y, pool);
    }
    {   int th = 1024, bl = N_NODES / 16;
        gather2_kernel<<<bl, th, 0, stream>>>(y, rowptr, col, batch, pool);
    }
    {   int th = 256, bl = (N_GRAPHS * 64) / th;
        mlp_kernel<<<bl, th, 0, stream>>>(pool, batch, Wm1, bm1, Wm2, bm2, out);
    }
}